// Round 6
// baseline (829.899 us; speedup 1.0000x reference)
//
#include <hip/hip_runtime.h>
#include <hip/hip_bf16.h>
#include <cstdint>
#include <cstddef>

#define N_S 4096
#define N_Kn 8192
#define HID 1024
#define SENT 1024
#define K3 3072

typedef __attribute__((ext_vector_type(4))) float f4;
typedef __attribute__((ext_vector_type(8))) short bf8;
typedef __attribute__((ext_vector_type(4))) short bf4;
typedef unsigned short u16;

__device__ __forceinline__ u16 f2bf(float x) {
    __hip_bfloat16 h = __float2bfloat16(x);   // HW RNE
    return __builtin_bit_cast(u16, h);
}
__device__ __forceinline__ float bf2f(u16 u) {
    union { unsigned int u; float f; } v; v.u = ((unsigned int)u) << 16;
    return v.f;
}

// async global->LDS, 16 bytes per lane; LDS dest = wave-uniform base + lane*16
__device__ __forceinline__ void gl16(const u16* g, u16* l) {
    __builtin_amdgcn_global_load_lds(
        (const __attribute__((address_space(1))) void*)g,
        (__attribute__((address_space(3))) void*)l, 16, 0, 0);
}

// bijective XCD swizzle (nwg % 8 == 0)
__device__ __forceinline__ int xcd_swz(int bid, int nwg) {
    const int cpx = nwg >> 3;
    return (bid & 7) * cpx + (bid >> 3);
}

// ---------------------------------------------------------------------------
// Transposes
// ---------------------------------------------------------------------------
__global__ __launch_bounds__(256) void transpose_split_f32(
    const float* __restrict__ in, u16* __restrict__ hi, u16* __restrict__ lo,
    int R, int C)
{
    __shared__ float tile[32][33];
    const int bx = blockIdx.x * 32, by = blockIdx.y * 32;
    const int tx = threadIdx.x & 31, ty = threadIdx.x >> 5;
#pragma unroll
    for (int i = 0; i < 32; i += 8)
        tile[ty + i][tx] = in[(size_t)(by + ty + i) * C + bx + tx];
    __syncthreads();
#pragma unroll
    for (int i = 0; i < 32; i += 8) {
        const float v = tile[tx][ty + i];
        const u16 h = f2bf(v);
        const size_t o = (size_t)(bx + ty + i) * R + by + tx;
        hi[o] = h;
        lo[o] = f2bf(v - bf2f(h));
    }
}

__global__ __launch_bounds__(256) void transpose_f32_bf16(
    const float* __restrict__ in, u16* __restrict__ out, int R, int C)
{
    __shared__ float tile[32][33];
    const int bx = blockIdx.x * 32, by = blockIdx.y * 32;
    const int tx = threadIdx.x & 31, ty = threadIdx.x >> 5;
#pragma unroll
    for (int i = 0; i < 32; i += 8)
        tile[ty + i][tx] = in[(size_t)(by + ty + i) * C + bx + tx];
    __syncthreads();
#pragma unroll
    for (int i = 0; i < 32; i += 8)
        out[(size_t)(bx + ty + i) * R + by + tx] = f2bf(tile[tx][ty + i]);
}

// ---------------------------------------------------------------------------
// gemm8: C[M][N] = A @ B^T, A [M][K] bf16, B [N][K] bf16, f32 out.
// 256x256 tile, BK=64, 512 thr (8 waves, 2Mx4N), 8-phase schedule (T3+T4),
// setprio around MFMA (T5), chunk-XOR LDS swizzle (T2, pre-swizzled source).
// LDS = 2 dbuf x 2 half x [128][64] x {A,B} = 128 KiB. 1 block/CU.
// Schedule per iter (2 K-tiles): phases 0-3 compute buf0 (stage next-odd
// K-tile into buf1 at phases 0,1); phases 4-7 compute buf1 (stage next-even
// into buf0 at phases 4,5). vmcnt(0)+barrier only at phases 3 and 7.
// ---------------------------------------------------------------------------
__global__ __launch_bounds__(512, 2) void gemm8(
    const u16* __restrict__ A, const u16* __restrict__ B,
    float* __restrict__ C, int N, int Kd, int gx)
{
    __shared__ u16 sA[2][2][8192];
    __shared__ u16 sB[2][2][8192];

    const int swz = xcd_swz(blockIdx.x, gridDim.x);
    const int bx = swz % gx, by = swz / gx;
    const long brow = (long)by * 256, bcol = (long)bx * 256;

    const int t = threadIdx.x;
    const int w = t >> 6, l = t & 63;
    const int fr = l & 15, kg = l >> 4;
    const int wm = w >> 2;           // this wave's A half (0/1)
    const int wn = w & 3;
    const int hb = wn >> 1;          // this wave's B half (0/1)
    const int cb = (wn & 1) * 64;    // col base within B half

    // staging geometry: thread t covers row t>>3 (+64), source chunk
    // (t&7)^(row&7); LDS write is linear (wave base + lane*16).
    const int srow = t >> 3;
    const int schk = ((t & 7) ^ (srow & 7)) << 3;
    const int sldb = w << 9;         // wave-uniform LDS elem base

    auto stage = [&](const u16* g, u16* lds) {
        gl16(g + (long)srow * Kd + schk, lds + sldb);
        gl16(g + (long)(srow + 64) * Kd + schk, lds + 4096 + sldb);
    };

    f4 acc[8][4];
#pragma unroll
    for (int m = 0; m < 8; ++m)
#pragma unroll
        for (int n = 0; n < 4; ++n) acc[m][n] = (f4){0.f, 0.f, 0.f, 0.f};

    // phase: compute quadrant (mh,nh) of K-tile in `buf`; optionally stage
    // one matrix's two halves of K-tile at k-offset kts into buf^1.
    auto phase = [&](int buf, int mh, int nh, int stg, long kts, bool wait) {
        bf8 fa[4][2], fb[2][2];
#pragma unroll
        for (int m = 0; m < 4; ++m)
#pragma unroll
            for (int kk = 0; kk < 2; ++kk)
                fa[m][kk] = *(bf8*)&sA[buf][wm][
                    (mh * 64 + m * 16 + fr) * 64 + (((kk << 2) + kg) ^ (fr & 7)) * 8];
#pragma unroll
        for (int nn = 0; nn < 2; ++nn)
#pragma unroll
            for (int kk = 0; kk < 2; ++kk)
                fb[nn][kk] = *(bf8*)&sB[buf][hb][
                    (cb + nh * 32 + nn * 16 + fr) * 64 + (((kk << 2) + kg) ^ (fr & 7)) * 8];
        if (stg == 1) {
            stage(A + brow * Kd + kts, &sA[buf ^ 1][0][0]);
            stage(A + (brow + 128) * Kd + kts, &sA[buf ^ 1][1][0]);
        } else if (stg == 2) {
            stage(B + bcol * Kd + kts, &sB[buf ^ 1][0][0]);
            stage(B + (bcol + 128) * Kd + kts, &sB[buf ^ 1][1][0]);
        }
        __builtin_amdgcn_s_barrier();
        __builtin_amdgcn_s_setprio(1);
#pragma unroll
        for (int kk = 0; kk < 2; ++kk)
#pragma unroll
            for (int m = 0; m < 4; ++m)
#pragma unroll
                for (int nn = 0; nn < 2; ++nn)
                    acc[mh * 4 + m][nh * 2 + nn] = __builtin_amdgcn_mfma_f32_16x16x32_bf16(
                        fa[m][kk], fb[nn][kk], acc[mh * 4 + m][nh * 2 + nn], 0, 0, 0);
        __builtin_amdgcn_s_setprio(0);
        if (wait) asm volatile("s_waitcnt vmcnt(0)" ::: "memory");
        __builtin_amdgcn_s_barrier();
    };

    // prologue: stage K-tile 0 into buf 0
    stage(A + brow * Kd, &sA[0][0][0]);
    stage(A + (brow + 128) * Kd, &sA[0][1][0]);
    stage(B + bcol * Kd, &sB[0][0][0]);
    stage(B + (bcol + 128) * Kd, &sB[0][1][0]);
    asm volatile("s_waitcnt vmcnt(0)" ::: "memory");
    __builtin_amdgcn_s_barrier();

    const int NIT = Kd >> 7;   // 2 K-tiles (of 64) per iteration
    for (int it = 0; it < NIT; ++it) {
        const long k1 = ((long)(2 * it + 1)) << 6;
        const long k2 = ((long)(2 * it + 2)) << 6;
        const bool more = (it + 1 < NIT);
        phase(0, 0, 0, 1, k1, false);
        phase(0, 0, 1, 2, k1, false);
        phase(0, 1, 0, 0, 0, false);
        phase(0, 1, 1, 0, 0, true);
        phase(1, 0, 0, more ? 1 : 0, k2, false);
        phase(1, 0, 1, more ? 2 : 0, k2, false);
        phase(1, 1, 0, 0, 0, false);
        phase(1, 1, 1, 0, 0, true);
    }

    // epilogue: C/D layout col = lane&15, row = (lane>>4)*4 + reg
#pragma unroll
    for (int n = 0; n < 4; ++n) {
        const long c = bcol + wn * 64 + n * 16 + fr;
#pragma unroll
        for (int m = 0; m < 8; ++m) {
            const long r0 = brow + wm * 128 + m * 16 + kg * 4;
#pragma unroll
            for (int r = 0; r < 4; ++r)
                C[(r0 + r) * (long)N + c] = acc[m][n][r];
        }
    }
}

// ---------------------------------------------------------------------------
// gemm_mfma: C[M][N] = A[M][K] @ B^T (+ bias); SPLIT/AF32/EPIS as before.
// Block order: XCD chunk -> 4x4 supertiles (L2 working set ~4 MB).
// ---------------------------------------------------------------------------
template <bool SPLIT, bool AF32, bool EPIS>
__global__ __launch_bounds__(256) void gemm_mfma(
    const void* __restrict__ Aany, const u16* __restrict__ Alo_,
    const u16* __restrict__ Bhi_, const u16* __restrict__ Blo_,
    float* __restrict__ Cf, u16* __restrict__ Chi, u16* __restrict__ Clo,
    const float* __restrict__ bias, int N, int Kd, int gx)
{
    constexpr int SA = AF32 ? 48 : 32;
    __shared__ u16 sAh[128 * SA];
    __shared__ u16 sAl[SPLIT ? 128 * SA : 8];
    __shared__ u16 sBh[128 * 32];
    __shared__ u16 sBl[SPLIT ? 128 * 32 : 8];

    const int swz = xcd_swz(blockIdx.x, gridDim.x);
    const int nst_x = gx >> 2;
    const int st = swz >> 4, off = swz & 15;
    const int bxi = (st % nst_x) * 4 + (off & 3);
    const int byi = (st / nst_x) * 4 + (off >> 2);

    const int t = threadIdx.x;
    const int w = t >> 6;
    const int l = t & 63;
    const long brow = (long)byi * 128;
    const long bcol = (long)bxi * 128;

    const int grow = l >> 2;
    const int gcol = ((l & 3) ^ ((l >> 3) & 3)) * 8;   // pre-swizzled source chunk

    const int wr = (w >> 1) * 64;
    const int wc = (w & 1) * 64;
    const int fr = l & 15;
    const int kg = l >> 4;
    const int kq = (kg ^ ((fr >> 1) & 3)) * 8;         // swizzled read chunk

    f4 acc[4][4];
#pragma unroll
    for (int m = 0; m < 4; m++)
#pragma unroll
        for (int n = 0; n < 4; n++) acc[m][n] = (f4){0.f, 0.f, 0.f, 0.f};

    const int nkt = Kd >> 5;
    for (int kt = 0; kt < nkt; ++kt) {
        const int k0 = kt * 32;

#pragma unroll
        for (int i = 0; i < 2; ++i) {
            const long r = bcol + i * 64 + w * 16 + grow;
            const int lb = i * 2048 + w * 512;
            gl16(Bhi_ + r * Kd + k0 + gcol, sBh + lb);
            if constexpr (SPLIT) gl16(Blo_ + r * Kd + k0 + gcol, sBl + lb);
        }

        if constexpr (!AF32) {
            const u16* Ahi = (const u16*)Aany;
#pragma unroll
            for (int i = 0; i < 2; ++i) {
                const long r = brow + i * 64 + w * 16 + grow;
                const int lb = i * 2048 + w * 512;
                gl16(Ahi + r * Kd + k0 + gcol, sAh + lb);
                if constexpr (SPLIT) gl16(Alo_ + r * Kd + k0 + gcol, sAl + lb);
            }
        } else {
            const float* Af = (const float*)Aany;
            const int ar = w * 8 + (l >> 3);
            const int cF = (l & 7) * 4;
#pragma unroll
            for (int j = 0; j < 4; ++j) {
                const int r = j * 32 + ar;
                const f4 v = *(const f4*)(Af + (brow + r) * (long)Kd + k0 + cF);
                u16 h[4], lw[4];
#pragma unroll
                for (int q = 0; q < 4; ++q) {
                    h[q] = f2bf(v[q]);
                    if constexpr (SPLIT) lw[q] = f2bf(v[q] - bf2f(h[q]));
                }
                *(bf4*)&sAh[r * SA + cF] = *(bf4*)h;
                if constexpr (SPLIT) *(bf4*)&sAl[r * SA + cF] = *(bf4*)lw;
            }
        }
        __syncthreads();

        bf8 fah[4], fbh[4], fal[4], fbl[4];
#pragma unroll
        for (int m = 0; m < 4; ++m) {
            if constexpr (AF32) {
                fah[m] = *(bf8*)&sAh[(wr + m * 16 + fr) * SA + kg * 8];
                if constexpr (SPLIT) fal[m] = *(bf8*)&sAl[(wr + m * 16 + fr) * SA + kg * 8];
            } else {
                fah[m] = *(bf8*)&sAh[(wr + m * 16 + fr) * 32 + kq];
                if constexpr (SPLIT) fal[m] = *(bf8*)&sAl[(wr + m * 16 + fr) * 32 + kq];
            }
            fbh[m] = *(bf8*)&sBh[(wc + m * 16 + fr) * 32 + kq];
            if constexpr (SPLIT) fbl[m] = *(bf8*)&sBl[(wc + m * 16 + fr) * 32 + kq];
        }
#pragma unroll
        for (int m = 0; m < 4; ++m)
#pragma unroll
            for (int n = 0; n < 4; ++n) {
                acc[m][n] = __builtin_amdgcn_mfma_f32_16x16x32_bf16(fah[m], fbh[n], acc[m][n], 0, 0, 0);
                if constexpr (SPLIT) {
                    acc[m][n] = __builtin_amdgcn_mfma_f32_16x16x32_bf16(fah[m], fbl[n], acc[m][n], 0, 0, 0);
                    acc[m][n] = __builtin_amdgcn_mfma_f32_16x16x32_bf16(fal[m], fbh[n], acc[m][n], 0, 0, 0);
                }
            }
        __syncthreads();
    }

#pragma unroll
    for (int n = 0; n < 4; ++n) {
        const long c = bcol + wc + n * 16 + fr;
        float bv = 0.f;
        if constexpr (EPIS) bv = bias[c];
#pragma unroll
        for (int m = 0; m < 4; ++m) {
            const long r0 = brow + wr + m * 16 + kg * 4;
#pragma unroll
            for (int r = 0; r < 4; ++r) {
                const float v = acc[m][n][r] + bv;
                if constexpr (EPIS) {
                    const u16 h = f2bf(v);
                    Chi[(r0 + r) * (long)N + c] = h;
                    Clo[(r0 + r) * (long)N + c] = f2bf(v - bf2f(h));
                } else {
                    Cf[(r0 + r) * (long)N + c] = v;
                }
            }
        }
    }
}

// ---------------------------------------------------------------------------
// Column softmax over align [N_S rows][N_Kn cols] (softmax along axis 0)
// ---------------------------------------------------------------------------
#define RCHUNK 128

__global__ __launch_bounds__(256) void softmax_partial(
    const float* __restrict__ align, float* __restrict__ pm, float* __restrict__ ps)
{
    const int col = blockIdx.x * 256 + threadIdx.x;
    const int r0 = blockIdx.y * RCHUNK;
    float m = -3.4e38f;
    for (int r = 0; r < RCHUNK; r++)
        m = fmaxf(m, align[(size_t)(r0 + r) * N_Kn + col]);
    float s = 0.f;
    for (int r = 0; r < RCHUNK; r++)
        s += __expf(align[(size_t)(r0 + r) * N_Kn + col] - m);
    pm[(size_t)blockIdx.y * N_Kn + col] = m;
    ps[(size_t)blockIdx.y * N_Kn + col] = s;
}

__global__ __launch_bounds__(256) void softmax_combine(
    const float* __restrict__ pm, const float* __restrict__ ps,
    float* __restrict__ fm, float* __restrict__ fsinv)
{
    const int col = blockIdx.x * 256 + threadIdx.x;
    float m = -3.4e38f;
#pragma unroll
    for (int i = 0; i < 32; i++) m = fmaxf(m, pm[(size_t)i * N_Kn + col]);
    float s = 0.f;
#pragma unroll
    for (int i = 0; i < 32; i++)
        s += ps[(size_t)i * N_Kn + col] * __expf(pm[(size_t)i * N_Kn + col] - m);
    fm[col] = m;
    fsinv[col] = 1.f / s;
}

__global__ __launch_bounds__(256) void softmax_norm(
    float* __restrict__ align, u16* __restrict__ abf,
    const float* __restrict__ fm, const float* __restrict__ fsinv)
{
    const int col = blockIdx.x * 256 + threadIdx.x;
    const int r0 = blockIdx.y * RCHUNK;
    const float m = fm[col], si = fsinv[col];
    for (int r = 0; r < RCHUNK; r++) {
        const size_t idx = (size_t)(r0 + r) * N_Kn + col;
        const float v = __expf(align[idx] - m) * si;
        align[idx] = v;
        abf[idx] = f2bf(v);
    }
}

// ---------------------------------------------------------------------------
extern "C" void kernel_launch(void* const* d_in, const int* in_sizes, int n_in,
                              void* d_out, int out_size, void* d_ws, size_t ws_size,
                              hipStream_t stream)
{
    const float* sentences = (const float*)d_in[0];  // [4096][1024]
    const float* knowledge = (const float*)d_in[1];  // [8192][3072]
    const float* Ws = (const float*)d_in[2];         // [1024][1024]
    const float* bs = (const float*)d_in[3];         // [1024]
    const float* Wk = (const float*)d_in[4];         // [3072][1024]
    const float* bk = (const float*)d_in[5];         // [1024]

    float* out_fused = (float*)d_out;                        // [4096][3072]
    float* out_attn = (float*)d_out + (size_t)N_S * K3;      // [4096][8192]

    // workspace (~114 MB); first 64 MB reused as attn_bf16 after GEMM4
    char* w = (char*)d_ws;
    u16* attn_bf = (u16*)w;
    u16* WsT_hi = (u16*)w; w += (size_t)HID * SENT * 2;
    u16* WsT_lo = (u16*)w; w += (size_t)HID * SENT * 2;
    u16* WkT_hi = (u16*)w; w += (size_t)HID * K3 * 2;
    u16* WkT_lo = (u16*)w; w += (size_t)HID * K3 * 2;
    u16* S_hi   = (u16*)w; w += (size_t)N_S * HID * 2;
    u16* S_lo   = (u16*)w; w += (size_t)N_S * HID * 2;
    u16* K_hi   = (u16*)w; w += (size_t)N_Kn * HID * 2;
    u16* K_lo   = (u16*)w; w += (size_t)N_Kn * HID * 2;      // end = 64 MB
    u16* kT     = (u16*)w; w += (size_t)K3 * N_Kn * 2;
    float* pm   = (float*)w; w += (size_t)32 * N_Kn * 4;
    float* ps   = (float*)w; w += (size_t)32 * N_Kn * 4;
    float* fm   = (float*)w; w += (size_t)N_Kn * 4;
    float* fsv  = (float*)w; w += (size_t)N_Kn * 4;

    // 1. weight transposes (split) + knowledge^T (bf16)
    transpose_split_f32<<<dim3(HID / 32, SENT / 32), 256, 0, stream>>>(Ws, WsT_hi, WsT_lo, SENT, HID);
    transpose_split_f32<<<dim3(HID / 32, K3 / 32), 256, 0, stream>>>(Wk, WkT_hi, WkT_lo, K3, HID);
    transpose_f32_bf16<<<dim3(K3 / 32, N_Kn / 32), 256, 0, stream>>>(knowledge, kT, N_Kn, K3);

    // 2. S = sentences @ Ws + bs -> split bf16
    gemm_mfma<true, true, true><<<(HID / 128) * (N_S / 128), 256, 0, stream>>>(
        sentences, nullptr, WsT_hi, WsT_lo, nullptr, S_hi, S_lo, bs, HID, SENT, HID / 128);

    // 3. K = knowledge @ Wk + bk -> split bf16
    gemm_mfma<true, true, true><<<(HID / 128) * (N_Kn / 128), 256, 0, stream>>>(
        knowledge, nullptr, WkT_hi, WkT_lo, nullptr, K_hi, K_lo, bk, HID, K3, HID / 128);

    // 4. align = S @ K^T -> f32 into attentions slot
    gemm_mfma<true, false, false><<<(N_Kn / 128) * (N_S / 128), 256, 0, stream>>>(
        S_hi, S_lo, K_hi, K_lo, out_attn, nullptr, nullptr, nullptr, N_Kn, HID, N_Kn / 128);

    // 5. column softmax (axis 0), in place; emit bf16 attn into reused ws
    softmax_partial<<<dim3(N_Kn / 256, N_S / RCHUNK), 256, 0, stream>>>(out_attn, pm, ps);
    softmax_combine<<<dim3(N_Kn / 256), 256, 0, stream>>>(pm, ps, fm, fsv);
    softmax_norm<<<dim3(N_Kn / 256, N_S / RCHUNK), 256, 0, stream>>>(out_attn, attn_bf, fm, fsv);

    // 6. fused = attn_bf16 @ kT -> f32 (256^2 8-phase)
    gemm8<<<(K3 / 256) * (N_S / 256), 512, 0, stream>>>(
        attn_bf, kT, out_fused, K3, N_Kn, K3 / 256);
}

// Round 7
// 783.538 us; speedup vs baseline: 1.0592x; 1.0592x over previous
//
#include <hip/hip_runtime.h>
#include <hip/hip_bf16.h>
#include <cstdint>
#include <cstddef>

#define N_S 4096
#define N_Kn 8192
#define HID 1024
#define SENT 1024
#define K3 3072

typedef __attribute__((ext_vector_type(4))) float f4;
typedef __attribute__((ext_vector_type(8))) short bf8;
typedef __attribute__((ext_vector_type(4))) short bf4;
typedef unsigned short u16;

__device__ __forceinline__ u16 f2bf(float x) {
    __hip_bfloat16 h = __float2bfloat16(x);   // HW RNE
    return __builtin_bit_cast(u16, h);
}
__device__ __forceinline__ float bf2f(u16 u) {
    union { unsigned int u; float f; } v; v.u = ((unsigned int)u) << 16;
    return v.f;
}

// async global->LDS, 16 bytes per lane; LDS dest = wave-uniform base + lane*16
__device__ __forceinline__ void gl16(const u16* g, u16* l) {
    __builtin_amdgcn_global_load_lds(
        (const __attribute__((address_space(1))) void*)g,
        (__attribute__((address_space(3))) void*)l, 16, 0, 0);
}

// bijective XCD swizzle (nwg % 8 == 0)
__device__ __forceinline__ int xcd_swz(int bid, int nwg) {
    const int cpx = nwg >> 3;
    return (bid & 7) * cpx + (bid >> 3);
}

// ---------------------------------------------------------------------------
// Transposes
// ---------------------------------------------------------------------------
__global__ __launch_bounds__(256) void transpose_split_f32(
    const float* __restrict__ in, u16* __restrict__ hi, u16* __restrict__ lo,
    int R, int C)
{
    __shared__ float tile[32][33];
    const int bx = blockIdx.x * 32, by = blockIdx.y * 32;
    const int tx = threadIdx.x & 31, ty = threadIdx.x >> 5;
#pragma unroll
    for (int i = 0; i < 32; i += 8)
        tile[ty + i][tx] = in[(size_t)(by + ty + i) * C + bx + tx];
    __syncthreads();
#pragma unroll
    for (int i = 0; i < 32; i += 8) {
        const float v = tile[tx][ty + i];
        const u16 h = f2bf(v);
        const size_t o = (size_t)(bx + ty + i) * R + by + tx;
        hi[o] = h;
        lo[o] = f2bf(v - bf2f(h));
    }
}

__global__ __launch_bounds__(256) void transpose_f32_bf16(
    const float* __restrict__ in, u16* __restrict__ out, int R, int C)
{
    __shared__ float tile[32][33];
    const int bx = blockIdx.x * 32, by = blockIdx.y * 32;
    const int tx = threadIdx.x & 31, ty = threadIdx.x >> 5;
#pragma unroll
    for (int i = 0; i < 32; i += 8)
        tile[ty + i][tx] = in[(size_t)(by + ty + i) * C + bx + tx];
    __syncthreads();
#pragma unroll
    for (int i = 0; i < 32; i += 8)
        out[(size_t)(bx + ty + i) * R + by + tx] = f2bf(tile[tx][ty + i]);
}

// ---------------------------------------------------------------------------
// gemm8: C[M][N] = A @ B^T, A [M][K] bf16, B [N][K] bf16, f32 out.
// 256x256 tile, BK=64, 512 thr (8 waves, 2Mx4N). 8-phase schedule with
// register fragment caching (24 ds_read_b128 per K-tile per wave), counted
// vmcnt(8) at phases 3/7, chunk-XOR LDS swizzle (pre-swizzled source),
// setprio around MFMA. LDS = 128 KiB.
// Quadrants per K-tile: (mh,nh) = (0,0),(0,1),(1,0),(1,1):
//   A-frags read ph0 (mh0) / ph2 (mh1); B-nh0 read ph0, B-nh1 read ph1.
//   -> B halves of buf are dead after ph1, A halves after ph2, so tile t+2
//   stages into the SAME buf at ph2 (B) / ph3 (A): flight 4-6 phases.
// ---------------------------------------------------------------------------
#define G8_LDA(buf, mh) \
  _Pragma("unroll") for (int m_ = 0; m_ < 4; ++m_) \
  _Pragma("unroll") for (int kk_ = 0; kk_ < 2; ++kk_) \
    fa[m_][kk_] = *(const bf8*)&sA[buf][wm][((mh)*64 + m_*16 + fr)*64 + (((kk_*4+kg) ^ (fr&7))<<3)];

#define G8_LDB(buf, nh, FB) \
  _Pragma("unroll") for (int nn_ = 0; nn_ < 2; ++nn_) \
  _Pragma("unroll") for (int kk_ = 0; kk_ < 2; ++kk_) \
    FB[nn_][kk_] = *(const bf8*)&sB[buf][hb][(cb + (nh)*32 + nn_*16 + fr)*64 + (((kk_*4+kg) ^ (fr&7))<<3)];

#define G8_MMA(mh, nh, FB) \
  _Pragma("unroll") for (int kk_ = 0; kk_ < 2; ++kk_) \
  _Pragma("unroll") for (int m_ = 0; m_ < 4; ++m_) \
  _Pragma("unroll") for (int nn_ = 0; nn_ < 2; ++nn_) \
    acc[(mh)*4+m_][(nh)*2+nn_] = __builtin_amdgcn_mfma_f32_16x16x32_bf16( \
        fa[m_][kk_], FB[nn_][kk_], acc[(mh)*4+m_][(nh)*2+nn_], 0, 0, 0);

#define BARR __builtin_amdgcn_s_barrier()
#define PRIO1 __builtin_amdgcn_s_setprio(1)
#define PRIO0 __builtin_amdgcn_s_setprio(0)
#define VM8  asm volatile("s_waitcnt vmcnt(8)" ::: "memory")
#define VM0  asm volatile("s_waitcnt vmcnt(0)" ::: "memory")

__global__ __launch_bounds__(512, 2) void gemm8(
    const u16* __restrict__ A, const u16* __restrict__ B,
    float* __restrict__ C, int N, int Kd, int gx)
{
    __shared__ u16 sA[2][2][8192];   // [buf][row-half 128][128x64]
    __shared__ u16 sB[2][2][8192];   // [buf][col-half 128][128x64]

    const int swz = xcd_swz(blockIdx.x, gridDim.x);
    const int bx = swz % gx, by = swz / gx;
    const long brow = (long)by * 256, bcol = (long)bx * 256;

    const int t = threadIdx.x;
    const int w = t >> 6, l = t & 63;
    const int fr = l & 15, kg = l >> 4;
    const int wm = w >> 2;           // wave's A half
    const int wn = w & 3;
    const int hb = wn >> 1;          // wave's B half
    const int cb = (wn & 1) * 64;    // col base within B half

    // staging geometry: thread t covers rows (t>>3) and (t>>3)+64 of a half,
    // source chunk (t&7)^(row&7); LDS write linear (wave base + lane*16).
    const int srow = t >> 3;
    const int schk = ((t & 7) ^ (srow & 7)) << 3;
    const int sldb = w << 9;

    auto stA = [&](int buf, int h, int kt) {
        const u16* g = A + (brow + h * 128 + srow) * (long)Kd + ((long)kt << 6) + schk;
        gl16(g, &sA[buf][h][sldb]);
        gl16(g + 64 * (long)Kd, &sA[buf][h][4096 + sldb]);
    };
    auto stB = [&](int buf, int h, int kt) {
        const u16* g = B + (bcol + h * 128 + srow) * (long)Kd + ((long)kt << 6) + schk;
        gl16(g, &sB[buf][h][sldb]);
        gl16(g + 64 * (long)Kd, &sB[buf][h][4096 + sldb]);
    };

    f4 acc[8][4];
#pragma unroll
    for (int m = 0; m < 8; ++m)
#pragma unroll
        for (int n = 0; n < 4; ++n) acc[m][n] = (f4){0.f, 0.f, 0.f, 0.f};

    bf8 fa[4][2], fb0[2][2], fb1[2][2];

    const int NK = Kd >> 6;   // 64-wide K-tiles (even for all our shapes)

    // prologue: tile 0 -> buf0, tile 1 -> buf1; wait tile 0 only
    stB(0, 0, 0); stB(0, 1, 0); stA(0, 0, 0); stA(0, 1, 0);
    stB(1, 0, 1); stB(1, 1, 1); stA(1, 0, 1); stA(1, 1, 1);
    VM8;
    BARR;

    for (int it = 0; it < (NK >> 1); ++it) {
        const int t2 = 2 * it + 2, t3 = 2 * it + 3;
        const bool s2 = t2 < NK, s3 = t3 < NK;

        // ---- tile 2it in buf0 ----
        // ph0: Q(0,0)
        G8_LDA(0, 0); G8_LDB(0, 0, fb0);
        BARR; PRIO1; G8_MMA(0, 0, fb0); PRIO0; BARR;
        // ph1: Q(0,1)
        G8_LDB(0, 1, fb1);
        BARR; PRIO1; G8_MMA(0, 1, fb1); PRIO0; BARR;
        // ph2: Q(1,0)  [B halves of buf0 now dead -> stage t+2 B]
        G8_LDA(0, 1);
        if (s2) { stB(0, 0, t2); stB(0, 1, t2); }
        BARR; PRIO1; G8_MMA(1, 0, fb0); PRIO0; BARR;
        // ph3: Q(1,1)  [A halves dead -> stage t+2 A]; counted drain
        if (s2) { stA(0, 0, t2); stA(0, 1, t2); }
        BARR; PRIO1; G8_MMA(1, 1, fb1); PRIO0;
        if (s2) { VM8; } else { VM0; }
        BARR;

        // ---- tile 2it+1 in buf1 ----
        // ph4
        G8_LDA(1, 0); G8_LDB(1, 0, fb0);
        BARR; PRIO1; G8_MMA(0, 0, fb0); PRIO0; BARR;
        // ph5
        G8_LDB(1, 1, fb1);
        BARR; PRIO1; G8_MMA(0, 1, fb1); PRIO0; BARR;
        // ph6
        G8_LDA(1, 1);
        if (s3) { stB(1, 0, t3); stB(1, 1, t3); }
        BARR; PRIO1; G8_MMA(1, 0, fb0); PRIO0; BARR;
        // ph7
        if (s3) { stA(1, 0, t3); stA(1, 1, t3); }
        BARR; PRIO1; G8_MMA(1, 1, fb1); PRIO0;
        if (s3) { VM8; } else { VM0; }
        BARR;
    }

    // epilogue: C/D layout col = lane&15, row = (lane>>4)*4 + reg
#pragma unroll
    for (int n = 0; n < 4; ++n) {
        const long c = bcol + wn * 64 + n * 16 + fr;
#pragma unroll
        for (int m = 0; m < 8; ++m) {
            const long r0 = brow + wm * 128 + m * 16 + kg * 4;
#pragma unroll
            for (int r = 0; r < 4; ++r)
                C[(r0 + r) * (long)N + c] = acc[m][n][r];
        }
    }
}

// ---------------------------------------------------------------------------
// gemm_mfma: C[M][N] = A[M][K] @ B^T (+ bias); SPLIT/AF32/EPIS as before.
// Block order: XCD chunk -> 4x4 supertiles (L2 working set ~4 MB).
// ---------------------------------------------------------------------------
template <bool SPLIT, bool AF32, bool EPIS>
__global__ __launch_bounds__(256) void gemm_mfma(
    const void* __restrict__ Aany, const u16* __restrict__ Alo_,
    const u16* __restrict__ Bhi_, const u16* __restrict__ Blo_,
    float* __restrict__ Cf, u16* __restrict__ Chi, u16* __restrict__ Clo,
    const float* __restrict__ bias, int N, int Kd, int gx)
{
    constexpr int SA = AF32 ? 48 : 32;
    __shared__ u16 sAh[128 * SA];
    __shared__ u16 sAl[SPLIT ? 128 * SA : 8];
    __shared__ u16 sBh[128 * 32];
    __shared__ u16 sBl[SPLIT ? 128 * 32 : 8];

    const int swz = xcd_swz(blockIdx.x, gridDim.x);
    const int nst_x = gx >> 2;
    const int st = swz >> 4, off = swz & 15;
    const int bxi = (st % nst_x) * 4 + (off & 3);
    const int byi = (st / nst_x) * 4 + (off >> 2);

    const int t = threadIdx.x;
    const int w = t >> 6;
    const int l = t & 63;
    const long brow = (long)byi * 128;
    const long bcol = (long)bxi * 128;

    const int grow = l >> 2;
    const int gcol = ((l & 3) ^ ((l >> 3) & 3)) * 8;   // pre-swizzled source chunk

    const int wr = (w >> 1) * 64;
    const int wc = (w & 1) * 64;
    const int fr = l & 15;
    const int kg = l >> 4;
    const int kq = (kg ^ ((fr >> 1) & 3)) * 8;         // swizzled read chunk

    f4 acc[4][4];
#pragma unroll
    for (int m = 0; m < 4; m++)
#pragma unroll
        for (int n = 0; n < 4; n++) acc[m][n] = (f4){0.f, 0.f, 0.f, 0.f};

    const int nkt = Kd >> 5;
    for (int kt = 0; kt < nkt; ++kt) {
        const int k0 = kt * 32;

#pragma unroll
        for (int i = 0; i < 2; ++i) {
            const long r = bcol + i * 64 + w * 16 + grow;
            const int lb = i * 2048 + w * 512;
            gl16(Bhi_ + r * Kd + k0 + gcol, sBh + lb);
            if constexpr (SPLIT) gl16(Blo_ + r * Kd + k0 + gcol, sBl + lb);
        }

        if constexpr (!AF32) {
            const u16* Ahi = (const u16*)Aany;
#pragma unroll
            for (int i = 0; i < 2; ++i) {
                const long r = brow + i * 64 + w * 16 + grow;
                const int lb = i * 2048 + w * 512;
                gl16(Ahi + r * Kd + k0 + gcol, sAh + lb);
                if constexpr (SPLIT) gl16(Alo_ + r * Kd + k0 + gcol, sAl + lb);
            }
        } else {
            const float* Af = (const float*)Aany;
            const int ar = w * 8 + (l >> 3);
            const int cF = (l & 7) * 4;
#pragma unroll
            for (int j = 0; j < 4; ++j) {
                const int r = j * 32 + ar;
                const f4 v = *(const f4*)(Af + (brow + r) * (long)Kd + k0 + cF);
                u16 h[4], lw[4];
#pragma unroll
                for (int q = 0; q < 4; ++q) {
                    h[q] = f2bf(v[q]);
                    if constexpr (SPLIT) lw[q] = f2bf(v[q] - bf2f(h[q]));
                }
                *(bf4*)&sAh[r * SA + cF] = *(bf4*)h;
                if constexpr (SPLIT) *(bf4*)&sAl[r * SA + cF] = *(bf4*)lw;
            }
        }
        __syncthreads();

        bf8 fah[4], fbh[4], fal[4], fbl[4];
#pragma unroll
        for (int m = 0; m < 4; ++m) {
            if constexpr (AF32) {
                fah[m] = *(bf8*)&sAh[(wr + m * 16 + fr) * SA + kg * 8];
                if constexpr (SPLIT) fal[m] = *(bf8*)&sAl[(wr + m * 16 + fr) * SA + kg * 8];
            } else {
                fah[m] = *(bf8*)&sAh[(wr + m * 16 + fr) * 32 + kq];
                if constexpr (SPLIT) fal[m] = *(bf8*)&sAl[(wr + m * 16 + fr) * 32 + kq];
            }
            fbh[m] = *(bf8*)&sBh[(wc + m * 16 + fr) * 32 + kq];
            if constexpr (SPLIT) fbl[m] = *(bf8*)&sBl[(wc + m * 16 + fr) * 32 + kq];
        }
#pragma unroll
        for (int m = 0; m < 4; ++m)
#pragma unroll
            for (int n = 0; n < 4; ++n) {
                acc[m][n] = __builtin_amdgcn_mfma_f32_16x16x32_bf16(fah[m], fbh[n], acc[m][n], 0, 0, 0);
                if constexpr (SPLIT) {
                    acc[m][n] = __builtin_amdgcn_mfma_f32_16x16x32_bf16(fah[m], fbl[n], acc[m][n], 0, 0, 0);
                    acc[m][n] = __builtin_amdgcn_mfma_f32_16x16x32_bf16(fal[m], fbh[n], acc[m][n], 0, 0, 0);
                }
            }
        __syncthreads();
    }

#pragma unroll
    for (int n = 0; n < 4; ++n) {
        const long c = bcol + wc + n * 16 + fr;
        float bv = 0.f;
        if constexpr (EPIS) bv = bias[c];
#pragma unroll
        for (int m = 0; m < 4; ++m) {
            const long r0 = brow + wr + m * 16 + kg * 4;
#pragma unroll
            for (int r = 0; r < 4; ++r) {
                const float v = acc[m][n][r] + bv;
                if constexpr (EPIS) {
                    const u16 h = f2bf(v);
                    Chi[(r0 + r) * (long)N + c] = h;
                    Clo[(r0 + r) * (long)N + c] = f2bf(v - bf2f(h));
                } else {
                    Cf[(r0 + r) * (long)N + c] = v;
                }
            }
        }
    }
}

// ---------------------------------------------------------------------------
// Column softmax over align [N_S rows][N_Kn cols] (softmax along axis 0)
// ---------------------------------------------------------------------------
#define RCHUNK 128

__global__ __launch_bounds__(256) void softmax_partial(
    const float* __restrict__ align, float* __restrict__ pm, float* __restrict__ ps)
{
    const int col = blockIdx.x * 256 + threadIdx.x;
    const int r0 = blockIdx.y * RCHUNK;
    float m = -3.4e38f;
    for (int r = 0; r < RCHUNK; r++)
        m = fmaxf(m, align[(size_t)(r0 + r) * N_Kn + col]);
    float s = 0.f;
    for (int r = 0; r < RCHUNK; r++)
        s += __expf(align[(size_t)(r0 + r) * N_Kn + col] - m);
    pm[(size_t)blockIdx.y * N_Kn + col] = m;
    ps[(size_t)blockIdx.y * N_Kn + col] = s;
}

__global__ __launch_bounds__(256) void softmax_combine(
    const float* __restrict__ pm, const float* __restrict__ ps,
    float* __restrict__ fm, float* __restrict__ fsinv)
{
    const int col = blockIdx.x * 256 + threadIdx.x;
    float m = -3.4e38f;
#pragma unroll
    for (int i = 0; i < 32; i++) m = fmaxf(m, pm[(size_t)i * N_Kn + col]);
    float s = 0.f;
#pragma unroll
    for (int i = 0; i < 32; i++)
        s += ps[(size_t)i * N_Kn + col] * __expf(pm[(size_t)i * N_Kn + col] - m);
    fm[col] = m;
    fsinv[col] = 1.f / s;
}

__global__ __launch_bounds__(256) void softmax_norm(
    float* __restrict__ align, u16* __restrict__ abf,
    const float* __restrict__ fm, const float* __restrict__ fsinv)
{
    const int col = blockIdx.x * 256 + threadIdx.x;
    const int r0 = blockIdx.y * RCHUNK;
    const float m = fm[col], si = fsinv[col];
    for (int r = 0; r < RCHUNK; r++) {
        const size_t idx = (size_t)(r0 + r) * N_Kn + col;
        const float v = __expf(align[idx] - m) * si;
        align[idx] = v;
        abf[idx] = f2bf(v);
    }
}

// ---------------------------------------------------------------------------
extern "C" void kernel_launch(void* const* d_in, const int* in_sizes, int n_in,
                              void* d_out, int out_size, void* d_ws, size_t ws_size,
                              hipStream_t stream)
{
    const float* sentences = (const float*)d_in[0];  // [4096][1024]
    const float* knowledge = (const float*)d_in[1];  // [8192][3072]
    const float* Ws = (const float*)d_in[2];         // [1024][1024]
    const float* bs = (const float*)d_in[3];         // [1024]
    const float* Wk = (const float*)d_in[4];         // [3072][1024]
    const float* bk = (const float*)d_in[5];         // [1024]

    float* out_fused = (float*)d_out;                        // [4096][3072]
    float* out_attn = (float*)d_out + (size_t)N_S * K3;      // [4096][8192]

    // workspace (~114 MB); first 64 MB reused as attn_bf16 after GEMM4
    char* w = (char*)d_ws;
    u16* attn_bf = (u16*)w;
    u16* WsT_hi = (u16*)w; w += (size_t)HID * SENT * 2;
    u16* WsT_lo = (u16*)w; w += (size_t)HID * SENT * 2;
    u16* WkT_hi = (u16*)w; w += (size_t)HID * K3 * 2;
    u16* WkT_lo = (u16*)w; w += (size_t)HID * K3 * 2;
    u16* S_hi   = (u16*)w; w += (size_t)N_S * HID * 2;
    u16* S_lo   = (u16*)w; w += (size_t)N_S * HID * 2;
    u16* K_hi   = (u16*)w; w += (size_t)N_Kn * HID * 2;
    u16* K_lo   = (u16*)w; w += (size_t)N_Kn * HID * 2;      // end = 64 MB
    u16* kT     = (u16*)w; w += (size_t)K3 * N_Kn * 2;
    float* pm   = (float*)w; w += (size_t)32 * N_Kn * 4;
    float* ps   = (float*)w; w += (size_t)32 * N_Kn * 4;
    float* fm   = (float*)w; w += (size_t)N_Kn * 4;
    float* fsv  = (float*)w; w += (size_t)N_Kn * 4;

    // 1. weight transposes (split) + knowledge^T (bf16)
    transpose_split_f32<<<dim3(HID / 32, SENT / 32), 256, 0, stream>>>(Ws, WsT_hi, WsT_lo, SENT, HID);
    transpose_split_f32<<<dim3(HID / 32, K3 / 32), 256, 0, stream>>>(Wk, WkT_hi, WkT_lo, K3, HID);
    transpose_f32_bf16<<<dim3(K3 / 32, N_Kn / 32), 256, 0, stream>>>(knowledge, kT, N_Kn, K3);

    // 2. S = sentences @ Ws + bs -> split bf16
    gemm_mfma<true, true, true><<<(HID / 128) * (N_S / 128), 256, 0, stream>>>(
        sentences, nullptr, WsT_hi, WsT_lo, nullptr, S_hi, S_lo, bs, HID, SENT, HID / 128);

    // 3. K = knowledge @ Wk + bk -> split bf16
    gemm_mfma<true, true, true><<<(HID / 128) * (N_Kn / 128), 256, 0, stream>>>(
        knowledge, nullptr, WkT_hi, WkT_lo, nullptr, K_hi, K_lo, bk, HID, K3, HID / 128);

    // 4. align = S @ K^T -> f32 into attentions slot
    gemm_mfma<true, false, false><<<(N_Kn / 128) * (N_S / 128), 256, 0, stream>>>(
        S_hi, S_lo, K_hi, K_lo, out_attn, nullptr, nullptr, nullptr, N_Kn, HID, N_Kn / 128);

    // 5. column softmax (axis 0), in place; emit bf16 attn into reused ws
    softmax_partial<<<dim3(N_Kn / 256, N_S / RCHUNK), 256, 0, stream>>>(out_attn, pm, ps);
    softmax_combine<<<dim3(N_Kn / 256), 256, 0, stream>>>(pm, ps, fm, fsv);
    softmax_norm<<<dim3(N_Kn / 256, N_S / RCHUNK), 256, 0, stream>>>(out_attn, attn_bf, fm, fsv);

    // 6. fused = attn_bf16 @ kT -> f32 (256^2 8-phase, fragment-cached)
    gemm8<<<(K3 / 256) * (N_S / 256), 512, 0, stream>>>(
        attn_bf, kT, out_fused, K3, N_Kn, K3 / 256);
}